// Round 12
// baseline (360.269 us; speedup 1.0000x reference)
//
#include <hip/hip_runtime.h>
#include <hip/hip_bf16.h>
#include <stdint.h>

typedef __bf16 bf16_t;
typedef __bf16 bf16x8 __attribute__((ext_vector_type(8)));
typedef float f32x4 __attribute__((ext_vector_type(4)));

#define B_  8
#define S_  1024
#define D_  1024
#define H_  16
#define DH_ 64

static __device__ __forceinline__ f32x4 mfma_bf16(bf16x8 a, bf16x8 b, f32x4 c) {
  return __builtin_amdgcn_mfma_f32_16x16x32_bf16(a, b, c, 0, 0, 0);
}

// async global->LDS, 16 bytes per lane; LDS dest = wave-uniform base + lane*16
#define GLOAD_LDS16(g, l)                                                     \
  __builtin_amdgcn_global_load_lds(                                           \
      (const __attribute__((address_space(1))) void*)(g),                     \
      (__attribute__((address_space(3))) void*)(l), 16, 0, 0)

// ---------------------------------------------------------------------------
// prep: fused {transpose4 | convert_qkv}. Blocks 0..1023: weight transpose
// (f32 [1024,1024] -> bf16 transposed). Blocks 1024..13311: Q/K/V f32->bf16.
// ---------------------------------------------------------------------------
__global__ __launch_bounds__(256) void prep(
    const float* __restrict__ q, const float* __restrict__ k,
    const float* __restrict__ v,
    const float* __restrict__ w0, const float* __restrict__ w1,
    const float* __restrict__ w2, const float* __restrict__ w3,
    bf16_t* __restrict__ qo, bf16_t* __restrict__ ko, bf16_t* __restrict__ vo,
    bf16_t* __restrict__ t0, bf16_t* __restrict__ t1,
    bf16_t* __restrict__ t2, bf16_t* __restrict__ t3)
{
  __shared__ float tile[64][65];
  const int bx = blockIdx.x;
  if (bx < 1024) {
    const int z = bx >> 8, rem = bx & 255;
    const int gx = rem & 15, gy = rem >> 4;
    const float* src; bf16_t* dst;
    switch (z) {
      case 0: src = w0; dst = t0; break;
      case 1: src = w1; dst = t1; break;
      case 2: src = w2; dst = t2; break;
      default: src = w3; dst = t3; break;
    }
    const int tx = threadIdx.x & 63;
    const int ty = threadIdx.x >> 6;
    const int c0 = gx * 64, r0 = gy * 64;
#pragma unroll
    for (int r = ty; r < 64; r += 4)
      tile[r][tx] = src[(size_t)(r0 + r) * 1024 + c0 + tx];
    __syncthreads();
#pragma unroll
    for (int r = ty; r < 64; r += 4)
      dst[(size_t)(c0 + r) * 1024 + r0 + tx] = (bf16_t)tile[tx][r];
  } else {
    const int idx = bx - 1024;
    const int zy = idx >> 12;          // 0..2
    const int gx = idx & 4095;
    const float* src; bf16_t* dst;
    switch (zy) {
      case 0: src = q; dst = qo; break;
      case 1: src = k; dst = ko; break;
      default: src = v; dst = vo; break;
    }
    const size_t i = ((size_t)gx * 256 + threadIdx.x) * 8;
    float4 a = *(const float4*)(src + i);
    float4 b = *(const float4*)(src + i + 4);
    bf16x8 o;
    o[0] = (bf16_t)a.x; o[1] = (bf16_t)a.y; o[2] = (bf16_t)a.z; o[3] = (bf16_t)a.w;
    o[4] = (bf16_t)b.x; o[5] = (bf16_t)b.y; o[6] = (bf16_t)b.z; o[7] = (bf16_t)b.w;
    *(bf16x8*)(dst + i) = o;
  }
}

// ---------------------------------------------------------------------------
// GEMM core: FROZEN Round-6 artifact (best measured; 60.x µs proj, 0
// conflicts, FETCH at minimum, ~850 TF = the plain-HIP 2-barrier ceiling).
// ---------------------------------------------------------------------------
#define BM_G 256
#define BN_G 128
#define BK_G 32
#define KDIM 1024
#define NK_G (KDIM / BK_G)                  // 32
#define AEL (BM_G * BK_G)                   // 8192 elems = 16 KB
#define BEL (BN_G * BK_G)                   // 4096 elems = 8 KB
#define LDS_BYTES ((2 * (AEL + BEL)) * 2)   // 49152 B

template <int MODE>
__device__ __forceinline__ void gemm_core(
    const bf16_t* __restrict__ Ap,   // fused [Mtot][1024]; rows via tileM
    const bf16_t* __restrict__ Bp,   // per-seg Bt
    void* __restrict__ Cp,           // per-seg C base
    bf16_t* smem, int tileM, int tileMloc, int tileN)
{
  bf16_t* const As = smem;                   // 2 x AEL
  bf16_t* const Bs = smem + 2 * AEL;         // 2 x BEL

  const int tid  = threadIdx.x;
  const int wv   = tid >> 6;                 // 0..7
  const int lane = tid & 63;
  const int wm   = wv >> 1;                  // 0..3 (M, 64 rows)
  const int wn   = wv & 1;                   // 0..1 (N, 64 cols)
  const int quad = lane >> 4;
  const int l15  = lane & 15;

  const int srow = wv * 16 + (lane >> 2);
  const int sg   = (((lane & 3) - (srow >> 1)) & 3) << 3;   // elems
  const bf16_t* gA = Ap + (size_t)(tileM * BM_G + srow) * KDIM + sg;
  const bf16_t* gB = Bp + (size_t)(tileN * BN_G + srow) * KDIM + sg;
  const int lw = wv * 512;                   // wave slice (elems) in a line

#define STAGE3(koff, buf) do {                                                \
    GLOAD_LDS16(gA + (koff),                     As + (buf) * AEL + lw);      \
    GLOAD_LDS16(gA + (size_t)128 * KDIM + (koff), As + (buf) * AEL + 4096 + lw); \
    GLOAD_LDS16(gB + (koff),                     Bs + (buf) * BEL + lw);      \
  } while (0)

  f32x4 acc[4][4];
#pragma unroll
  for (int mi = 0; mi < 4; ++mi)
#pragma unroll
    for (int ni = 0; ni < 4; ++ni)
      acc[mi][ni] = (f32x4){0.f, 0.f, 0.f, 0.f};

  STAGE3(0, 0);
  STAGE3(BK_G, 1);
  asm volatile("s_waitcnt vmcnt(3)" ::: "memory");
  __builtin_amdgcn_s_barrier();

  for (int t = 0; t < NK_G; ++t) {
    const int cbA = (t & 1) * AEL;
    const int cbB = (t & 1) * BEL;

    bf16x8 af[4], bfr[4];
#pragma unroll
    for (int mi = 0; mi < 4; ++mi) {
      const int row = wm * 64 + mi * 16 + l15;
      af[mi] = *(const bf16x8*)(As + cbA + row * BK_G + (((quad + (row >> 1)) & 3) << 3));
    }
#pragma unroll
    for (int ni = 0; ni < 4; ++ni) {
      const int row = wn * 64 + ni * 16 + l15;
      bfr[ni] = *(const bf16x8*)(Bs + cbB + row * BK_G + (((quad + (row >> 1)) & 3) << 3));
    }
    asm volatile("s_waitcnt lgkmcnt(0)" ::: "memory");
    __builtin_amdgcn_sched_barrier(0);
    __builtin_amdgcn_s_setprio(1);
#pragma unroll
    for (int mi = 0; mi < 4; ++mi)
#pragma unroll
      for (int ni = 0; ni < 4; ++ni)
        acc[mi][ni] = mfma_bf16(af[mi], bfr[ni], acc[mi][ni]);
    __builtin_amdgcn_s_setprio(0);
    __builtin_amdgcn_sched_barrier(0);
    asm volatile("" ::: "memory");
    __builtin_amdgcn_s_barrier();            // all waves done reading buf t&1

    if (t + 2 < NK_G) {
      STAGE3((size_t)(t + 2) * BK_G, t & 1); // overwrite just-consumed buf
      asm volatile("s_waitcnt vmcnt(3)" ::: "memory");  // tile t+1 landed
    } else if (t + 2 == NK_G) {
      asm volatile("s_waitcnt vmcnt(0)" ::: "memory");  // last tile landed
    }
    if (t + 1 < NK_G) {
      asm volatile("" ::: "memory");
      __builtin_amdgcn_s_barrier();
    }
  }
#undef STAGE3

  // epilogue: C/D frag layout col=l15(N), row=quad*4+r(M)
#pragma unroll
  for (int mi = 0; mi < 4; ++mi) {
#pragma unroll
    for (int ni = 0; ni < 4; ++ni) {
#pragma unroll
      for (int r = 0; r < 4; ++r) {
        const int row = tileMloc * BM_G + wm * 64 + mi * 16 + quad * 4 + r;
        const int col = tileN * BN_G + wn * 64 + ni * 16 + l15;
        if (MODE == 0) {
          ((float*)Cp)[(size_t)row * 1024 + col] = acc[mi][ni][r];
        } else {
          const int b = row >> 10, s = row & 1023;
          const int h = col >> 6,  d = col & 63;
          ((bf16_t*)Cp)[(((size_t)(b * H_ + h) << 10) | s) * DH_ + d] =
              (bf16_t)acc[mi][ni][r];
        }
      }
    }
  }
}

// Fused projection GEMM. grid (768,1,1), block 512, 48KB dyn LDS.
__global__ __launch_bounds__(512, 4) void gemm_proj(
    const bf16_t* __restrict__ A, const bf16_t* __restrict__ Bw,
    bf16_t* __restrict__ Cb)
{
  extern __shared__ bf16_t smem[];
  const int xcd = blockIdx.x & 7;
  const int r   = blockIdx.x >> 3;           // 0..95
  const int tileN = r & 7;                   // N fastest -> same-M co-resident
  const int tileM = xcd * 12 + (r >> 3);     // 0..95
  const int seg = tileM >> 5;                // 0..2
  gemm_core<1>(A, Bw + ((size_t)seg << 20), (void*)(Cb + ((size_t)seg << 23)),
               smem, tileM, tileM & 31, tileN);
}

// Output GEMM: f32 row-major C. grid (256,1,1), block 512, 48KB dyn LDS.
__global__ __launch_bounds__(512, 4) void gemm_out(
    const bf16_t* __restrict__ Ap, const bf16_t* __restrict__ Bp,
    float* __restrict__ Cp)
{
  extern __shared__ bf16_t smem[];
  const int xcd = blockIdx.x & 7;
  const int r   = blockIdx.x >> 3;           // 0..31
  const int tileN = r & 7;
  const int tileM = xcd * 4 + (r >> 3);      // 0..31
  gemm_core<0>(Ap, Bp, (void*)Cp, smem, tileM, tileM, tileN);
}

// ---------------------------------------------------------------------------
// Transpose V: [B,H,S,64] -> [B,H,64,S].  grid (16, 128): x=s-tile, y=b*H+h.
// ---------------------------------------------------------------------------
__global__ __launch_bounds__(256) void transposeV(
    const bf16_t* __restrict__ src, bf16_t* __restrict__ dst)
{
  __shared__ bf16_t t[64 * 72];     // row stride 72 elems (144B, 16B-aligned)
  const size_t base = (size_t)blockIdx.y * (64 * 1024);
  const int s0 = blockIdx.x * 64;
#pragma unroll
  for (int it = 0; it < 2; ++it) {
    const int c = it * 256 + threadIdx.x;
    const int r = c >> 3, col8 = (c & 7) * 8;
    bf16x8 v = *(const bf16x8*)(src + base + (size_t)(s0 + r) * 64 + col8);
    *(bf16x8*)(t + r * 72 + col8) = v;
  }
  __syncthreads();
#pragma unroll
  for (int it = 0; it < 2; ++it) {
    const int c = it * 256 + threadIdx.x;
    const int d = c >> 3, sc8 = (c & 7) * 8;
    bf16x8 v;
#pragma unroll
    for (int j = 0; j < 8; ++j) v[j] = t[(sc8 + j) * 72 + d];
    *(bf16x8*)(dst + base + (size_t)d * 1024 + s0 + sc8) = v;
  }
}

// ---------------------------------------------------------------------------
// Flash attention v5: NO K/V LDS staging — per (b,h) K+V = 256 KB and the
// h%8 XCD mapping gives each XCD 16 (b,h) pairs x 256 KB = 4 MB = L2, so
// staging L2-resident data through LDS was pure overhead (guide common-
// mistake #7, m169: dropping it = +26%). MFMA fragments are 16B-contiguous
// in the global layouts: K[B,H,S,64] frag = K[key][quad*8..]; V^T[B,H,64,S]
// frag = Vt[d][k0+quad*8..]. All 4 waves read the same K/V frags -> L1 hits.
// P round-trip stays in WAVE-PRIVATE LDS -> kernel is BARRIER-FREE;
// LDS 25.6 KB -> 9.2 KB (8 blocks/CU, was 6).
// Out: [B,S,H*64] bf16.  grid (H, S/64, B).
// ---------------------------------------------------------------------------
__global__ __launch_bounds__(256) void attn64(
    const bf16_t* __restrict__ Q,
    const bf16_t* __restrict__ Kv,
    const bf16_t* __restrict__ Vt,
    const int* __restrict__ valid_lens,
    bf16_t* __restrict__ O)
{
  const int h  = blockIdx.x;
  const int qt = blockIdx.y;
  const int b  = blockIdx.z;
  const int tid  = threadIdx.x;
  const int wave = tid >> 6;
  const int lane = tid & 63;
  const int quad = lane >> 4;
  const int l15  = lane & 15;

  const int L   = valid_lens[b];
  const int nkt = (L + 63) >> 6;

  const size_t base = ((size_t)(b * H_ + h)) * S_ * DH_;
  const bf16_t* Qp = Q  + base;
  const bf16_t* Kp = Kv + base;
  const bf16_t* Vp = Vt + base;     // [64][1024] per (b,h)

  __shared__ bf16_t Pb[4][16 * 72]; // per-wave P [q][key] (wave-private)
  bf16_t* const Pw = &Pb[wave][0];

  const int qrow = qt * 64 + wave * 16 + l15;
  const bf16x8 qf0 = *(const bf16x8*)(Qp + (size_t)qrow * DH_ + quad * 8);
  const bf16x8 qf1 = *(const bf16x8*)(Qp + (size_t)qrow * DH_ + 32 + quad * 8);

  f32x4 o[4];
  float lsum[4];
#pragma unroll
  for (int r = 0; r < 4; ++r) {
    o[r] = (f32x4){0.f, 0.f, 0.f, 0.f};
    lsum[r] = 0.f;
  }

  for (int kt = 0; kt < nkt; ++kt) {
    const int k0 = kt * 64;

    // ---- scores: S = Q K^T (K frags direct from global; L1/L2-resident) ----
    f32x4 sc[4];
#pragma unroll
    for (int n16 = 0; n16 < 4; ++n16) {
      const bf16_t* kr = Kp + (size_t)(k0 + n16 * 16 + l15) * DH_ + quad * 8;
      bf16x8 kf0 = *(const bf16x8*)(kr);
      bf16x8 kf1 = *(const bf16x8*)(kr + 32);
      f32x4 s = (f32x4){0.f, 0.f, 0.f, 0.f};
      s = mfma_bf16(qf0, kf0, s);
      s = mfma_bf16(qf1, kf1, s);
      sc[n16] = s;
    }

    // ---- p = exp(s/8) (no max subtraction), mask tail tile ----
    if (k0 + 64 <= L) {
#pragma unroll
      for (int n16 = 0; n16 < 4; ++n16) {
#pragma unroll
        for (int r = 0; r < 4; ++r) {
          const float p = __expf(sc[n16][r] * 0.125f);
          lsum[r] += p;
          Pw[(quad * 4 + r) * 72 + n16 * 16 + l15] = (bf16_t)p;
        }
      }
    } else {
#pragma unroll
      for (int n16 = 0; n16 < 4; ++n16) {
        const bool valid = (k0 + n16 * 16 + l15) < L;
#pragma unroll
        for (int r = 0; r < 4; ++r) {
          const float p = valid ? __expf(sc[n16][r] * 0.125f) : 0.f;
          lsum[r] += p;
          Pw[(quad * 4 + r) * 72 + n16 * 16 + l15] = (bf16_t)p;
        }
      }
    }

    // ---- O += P @ V (P wave-private LDS; V^T frags direct from global) ----
    const bf16x8 pf0 = *(const bf16x8*)(Pw + l15 * 72 + quad * 8);
    const bf16x8 pf1 = *(const bf16x8*)(Pw + l15 * 72 + 32 + quad * 8);
#pragma unroll
    for (int dt = 0; dt < 4; ++dt) {
      const bf16_t* vr = Vp + (size_t)(dt * 16 + l15) * S_ + k0 + quad * 8;
      bf16x8 vf0 = *(const bf16x8*)(vr);
      bf16x8 vf1 = *(const bf16x8*)(vr + 32);
      o[dt] = mfma_bf16(pf0, vf0, o[dt]);
      o[dt] = mfma_bf16(pf1, vf1, o[dt]);
    }
  }

  // ---- row-sum reduce, normalize, write [B,S,H*64] ----
  float inv[4];
#pragma unroll
  for (int r = 0; r < 4; ++r) {
    float t = lsum[r];
    t += __shfl_xor(t, 1, 64);
    t += __shfl_xor(t, 2, 64);
    t += __shfl_xor(t, 4, 64);
    t += __shfl_xor(t, 8, 64);
    inv[r] = 1.f / t;
  }
  const int qout = qt * 64 + wave * 16 + quad * 4;
#pragma unroll
  for (int dt = 0; dt < 4; ++dt) {
#pragma unroll
    for (int r = 0; r < 4; ++r) {
      const float v = o[dt][r] * inv[r];
      O[((size_t)(b * S_ + qout + r)) * (H_ * DH_) + h * DH_ + dt * 16 + l15] = (bf16_t)v;
    }
  }
}

// ---------------------------------------------------------------------------
extern "C" void kernel_launch(void* const* d_in, const int* in_sizes, int n_in,
                              void* d_out, int out_size, void* d_ws, size_t ws_size,
                              hipStream_t stream) {
  const float* queries = (const float*)d_in[0];
  const float* keys    = (const float*)d_in[1];
  const float* values  = (const float*)d_in[2];
  const float* Wq      = (const float*)d_in[3];
  const float* Wk      = (const float*)d_in[4];
  const float* Wv      = (const float*)d_in[5];
  const float* Wo      = (const float*)d_in[6];
  const int* valid_lens = (const int*)d_in[7];
  float* out = (float*)d_out;

  bf16_t* ws = (bf16_t*)d_ws;
  const size_t MB = 1024 * 1024;     // elements (bf16)
  bf16_t* WqT = ws + 0 * MB;         // WqT,WkT,WvT contiguous (seg<<20)
  bf16_t* WkT = ws + 1 * MB;
  bf16_t* WvT = ws + 2 * MB;
  bf16_t* WoT = ws + 3 * MB;
  bf16_t* Qc  = ws + 4 * MB;         // Qc,Kc,Vc contiguous -> fused A 24576x1024
  bf16_t* Kc  = ws + 12 * MB;
  bf16_t* Vc  = ws + 20 * MB;
  bf16_t* Qb  = ws + 28 * MB;        // Qb,Kb,Vb contiguous (seg<<23)
  bf16_t* Kb  = ws + 36 * MB;
  bf16_t* Vb  = ws + 44 * MB;
  bf16_t* VbT = ws + 52 * MB;        // [B,H,64,S] transposed V
  bf16_t* Ab  = ws + 60 * MB;        // [B,S,1024] attn out  (total 136 MB)

  (void)hipFuncSetAttribute((const void*)gemm_proj,
                            hipFuncAttributeMaxDynamicSharedMemorySize, LDS_BYTES);
  (void)hipFuncSetAttribute((const void*)gemm_out,
                            hipFuncAttributeMaxDynamicSharedMemorySize, LDS_BYTES);

  // 1) fused weight-transpose + QKV convert
  prep<<<dim3(1024 + 12288, 1, 1), 256, 0, stream>>>(
      queries, keys, values, Wq, Wk, Wv, Wo,
      Qc, Kc, Vc, WqT, WkT, WvT, WoT);

  // 2) fused Q/K/V projection (frozen R6 core)
  gemm_proj<<<dim3(768, 1, 1), 512, LDS_BYTES, stream>>>(Qc, WqT, Qb);

  // 3) V transpose
  transposeV<<<dim3(16, 128), 256, 0, stream>>>(Vb, VbT);

  // 4) attention (v5: no K/V staging, barrier-free)
  attn64<<<dim3(16, 16, 8), 256, 0, stream>>>(Qb, Kb, VbT, valid_lens, Ab);

  // 5) output projection
  gemm_out<<<dim3(256, 1, 1), 512, LDS_BYTES, stream>>>(Ab, WoT, out);
}

// Round 13
// 284.984 us; speedup vs baseline: 1.2642x; 1.2642x over previous
//
#include <hip/hip_runtime.h>
#include <hip/hip_bf16.h>
#include <stdint.h>

typedef __bf16 bf16_t;
typedef __bf16 bf16x8 __attribute__((ext_vector_type(8)));
typedef float f32x4 __attribute__((ext_vector_type(4)));

#define B_  8
#define S_  1024
#define D_  1024
#define H_  16
#define DH_ 64

static __device__ __forceinline__ f32x4 mfma_bf16(bf16x8 a, bf16x8 b, f32x4 c) {
  return __builtin_amdgcn_mfma_f32_16x16x32_bf16(a, b, c, 0, 0, 0);
}

// async global->LDS, 16 bytes per lane; LDS dest = wave-uniform base + lane*16
#define GLOAD_LDS16(g, l)                                                     \
  __builtin_amdgcn_global_load_lds(                                           \
      (const __attribute__((address_space(1))) void*)(g),                     \
      (__attribute__((address_space(3))) void*)(l), 16, 0, 0)

// ---------------------------------------------------------------------------
// Transpose four 1024x1024 f32 weights -> bf16 transposed: Wt[n][k] = W[k][n]
// grid (16,16,4), block 256
// ---------------------------------------------------------------------------
__global__ __launch_bounds__(256) void transpose4(
    const float* __restrict__ w0, const float* __restrict__ w1,
    const float* __restrict__ w2, const float* __restrict__ w3,
    bf16_t* __restrict__ t0, bf16_t* __restrict__ t1,
    bf16_t* __restrict__ t2, bf16_t* __restrict__ t3)
{
  __shared__ float tile[64][65];
  const float* src; bf16_t* dst;
  switch (blockIdx.z) {
    case 0: src = w0; dst = t0; break;
    case 1: src = w1; dst = t1; break;
    case 2: src = w2; dst = t2; break;
    default: src = w3; dst = t3; break;
  }
  const int tx = threadIdx.x & 63;
  const int ty = threadIdx.x >> 6;
  const int c0 = blockIdx.x * 64, r0 = blockIdx.y * 64;
#pragma unroll
  for (int r = ty; r < 64; r += 4)
    tile[r][tx] = src[(size_t)(r0 + r) * 1024 + c0 + tx];
  __syncthreads();
#pragma unroll
  for (int r = ty; r < 64; r += 4)
    dst[(size_t)(c0 + r) * 1024 + r0 + tx] = (bf16_t)tile[tx][r];
}

// ---------------------------------------------------------------------------
// Convert Q/K/V f32 -> bf16 (contiguous). grid (4096,3), block 256, 8 elem/thr.
// ---------------------------------------------------------------------------
__global__ __launch_bounds__(256) void convert_qkv(
    const float* __restrict__ q, const float* __restrict__ k,
    const float* __restrict__ v,
    bf16_t* __restrict__ qo, bf16_t* __restrict__ ko, bf16_t* __restrict__ vo)
{
  const float* src; bf16_t* dst;
  switch (blockIdx.y) {
    case 0: src = q; dst = qo; break;
    case 1: src = k; dst = ko; break;
    default: src = v; dst = vo; break;
  }
  const size_t i = ((size_t)blockIdx.x * 256 + threadIdx.x) * 8;
  float4 a = *(const float4*)(src + i);
  float4 b = *(const float4*)(src + i + 4);
  bf16x8 o;
  o[0] = (bf16_t)a.x; o[1] = (bf16_t)a.y; o[2] = (bf16_t)a.z; o[3] = (bf16_t)a.w;
  o[4] = (bf16_t)b.x; o[5] = (bf16_t)b.y; o[6] = (bf16_t)b.z; o[7] = (bf16_t)b.w;
  *(bf16x8*)(dst + i) = o;
}

// ---------------------------------------------------------------------------
// Transpose V: [B,H,S,64] -> [B,H,64,S].  grid (16, 128): x=s-tile, y=b*H+h.
// ---------------------------------------------------------------------------
__global__ __launch_bounds__(256) void transposeV(
    const bf16_t* __restrict__ src, bf16_t* __restrict__ dst)
{
  __shared__ bf16_t t[64 * 72];     // row stride 72 elems (144B, 16B-aligned)
  const size_t base = (size_t)blockIdx.y * (64 * 1024);
  const int s0 = blockIdx.x * 64;
#pragma unroll
  for (int it = 0; it < 2; ++it) {
    const int c = it * 256 + threadIdx.x;
    const int r = c >> 3, col8 = (c & 7) * 8;
    bf16x8 v = *(const bf16x8*)(src + base + (size_t)(s0 + r) * 64 + col8);
    *(bf16x8*)(t + r * 72 + col8) = v;
  }
  __syncthreads();
#pragma unroll
  for (int it = 0; it < 2; ++it) {
    const int c = it * 256 + threadIdx.x;
    const int d = c >> 3, sc8 = (c & 7) * 8;
    bf16x8 v;
#pragma unroll
    for (int j = 0; j < 8; ++j) v[j] = t[(sc8 + j) * 72 + d];
    *(bf16x8*)(dst + base + (size_t)d * 1024 + s0 + sc8) = v;
  }
}

// ---------------------------------------------------------------------------
// GEMM core: FROZEN Round-6 artifact (best measured TOTAL 284.5 µs; proj
// 60-62 µs, MfmaUtil 34-36%, 0 bank conflicts, FETCH at the 43 MB minimum).
//   BM=256, BN=128, BK=32; 512 thr = 8 waves (4M x 2N), 64x64 out per wave;
//   48 KB dbuf LDS -> 3 blocks/CU co-resident (the one mechanism that moved
//   MfmaUtil, R5->R6); counted vmcnt(3) never 0 mid-loop; additive swizzle
//   inverse-applied on the global source (rule #21).
// MODE: 0 = C f32 row-major; 1 = C bf16 scatter into [B,H,S,64].
// ---------------------------------------------------------------------------
#define BM_G 256
#define BN_G 128
#define BK_G 32
#define KDIM 1024
#define NK_G (KDIM / BK_G)                  // 32
#define AEL (BM_G * BK_G)                   // 8192 elems = 16 KB
#define BEL (BN_G * BK_G)                   // 4096 elems = 8 KB
#define LDS_BYTES ((2 * (AEL + BEL)) * 2)   // 49152 B

template <int MODE>
__device__ __forceinline__ void gemm_core(
    const bf16_t* __restrict__ Ap,   // fused [Mtot][1024]; rows via tileM
    const bf16_t* __restrict__ Bp,   // per-seg Bt
    void* __restrict__ Cp,           // per-seg C base
    bf16_t* smem, int tileM, int tileMloc, int tileN)
{
  bf16_t* const As = smem;                   // 2 x AEL
  bf16_t* const Bs = smem + 2 * AEL;         // 2 x BEL

  const int tid  = threadIdx.x;
  const int wv   = tid >> 6;                 // 0..7
  const int lane = tid & 63;
  const int wm   = wv >> 1;                  // 0..3 (M, 64 rows)
  const int wn   = wv & 1;                   // 0..1 (N, 64 cols)
  const int quad = lane >> 4;
  const int l15  = lane & 15;

  const int srow = wv * 16 + (lane >> 2);
  const int sg   = (((lane & 3) - (srow >> 1)) & 3) << 3;   // elems
  const bf16_t* gA = Ap + (size_t)(tileM * BM_G + srow) * KDIM + sg;
  const bf16_t* gB = Bp + (size_t)(tileN * BN_G + srow) * KDIM + sg;
  const int lw = wv * 512;                   // wave slice (elems) in a line

#define STAGE3(koff, buf) do {                                                \
    GLOAD_LDS16(gA + (koff),                     As + (buf) * AEL + lw);      \
    GLOAD_LDS16(gA + (size_t)128 * KDIM + (koff), As + (buf) * AEL + 4096 + lw); \
    GLOAD_LDS16(gB + (koff),                     Bs + (buf) * BEL + lw);      \
  } while (0)

  f32x4 acc[4][4];
#pragma unroll
  for (int mi = 0; mi < 4; ++mi)
#pragma unroll
    for (int ni = 0; ni < 4; ++ni)
      acc[mi][ni] = (f32x4){0.f, 0.f, 0.f, 0.f};

  STAGE3(0, 0);
  STAGE3(BK_G, 1);
  asm volatile("s_waitcnt vmcnt(3)" ::: "memory");
  __builtin_amdgcn_s_barrier();

  for (int t = 0; t < NK_G; ++t) {
    const int cbA = (t & 1) * AEL;
    const int cbB = (t & 1) * BEL;

    bf16x8 af[4], bfr[4];
#pragma unroll
    for (int mi = 0; mi < 4; ++mi) {
      const int row = wm * 64 + mi * 16 + l15;
      af[mi] = *(const bf16x8*)(As + cbA + row * BK_G + (((quad + (row >> 1)) & 3) << 3));
    }
#pragma unroll
    for (int ni = 0; ni < 4; ++ni) {
      const int row = wn * 64 + ni * 16 + l15;
      bfr[ni] = *(const bf16x8*)(Bs + cbB + row * BK_G + (((quad + (row >> 1)) & 3) << 3));
    }
    asm volatile("s_waitcnt lgkmcnt(0)" ::: "memory");
    __builtin_amdgcn_sched_barrier(0);
    __builtin_amdgcn_s_setprio(1);
#pragma unroll
    for (int mi = 0; mi < 4; ++mi)
#pragma unroll
      for (int ni = 0; ni < 4; ++ni)
        acc[mi][ni] = mfma_bf16(af[mi], bfr[ni], acc[mi][ni]);
    __builtin_amdgcn_s_setprio(0);
    __builtin_amdgcn_sched_barrier(0);
    asm volatile("" ::: "memory");
    __builtin_amdgcn_s_barrier();            // all waves done reading buf t&1

    if (t + 2 < NK_G) {
      STAGE3((size_t)(t + 2) * BK_G, t & 1); // overwrite just-consumed buf
      asm volatile("s_waitcnt vmcnt(3)" ::: "memory");  // tile t+1 landed
    } else if (t + 2 == NK_G) {
      asm volatile("s_waitcnt vmcnt(0)" ::: "memory");  // last tile landed
    }
    if (t + 1 < NK_G) {
      asm volatile("" ::: "memory");
      __builtin_amdgcn_s_barrier();
    }
  }
#undef STAGE3

  // epilogue: C/D frag layout col=l15(N), row=quad*4+r(M)
#pragma unroll
  for (int mi = 0; mi < 4; ++mi) {
#pragma unroll
    for (int ni = 0; ni < 4; ++ni) {
#pragma unroll
      for (int r = 0; r < 4; ++r) {
        const int row = tileMloc * BM_G + wm * 64 + mi * 16 + quad * 4 + r;
        const int col = tileN * BN_G + wn * 64 + ni * 16 + l15;
        if (MODE == 0) {
          ((float*)Cp)[(size_t)row * 1024 + col] = acc[mi][ni][r];
        } else {
          const int b = row >> 10, s = row & 1023;
          const int h = col >> 6,  d = col & 63;
          ((bf16_t*)Cp)[(((size_t)(b * H_ + h) << 10) | s) * DH_ + d] =
              (bf16_t)acc[mi][ni][r];
        }
      }
    }
  }
}

// Fused projection GEMM: A=[Qc;Kc;Vc] (24576x1024), seg = tileM>>5 selects
// weight (WqT/WkT/WvT contiguous) + output (Qb/Kb/Vb contiguous).
// grid (768,1,1), block 512 (8 waves), 48KB dyn LDS, 3 blocks/CU.
__global__ __launch_bounds__(512, 4) void gemm_proj(
    const bf16_t* __restrict__ A, const bf16_t* __restrict__ Bw,
    bf16_t* __restrict__ Cb)
{
  extern __shared__ bf16_t smem[];
  const int xcd = blockIdx.x & 7;
  const int r   = blockIdx.x >> 3;           // 0..95
  const int tileN = r & 7;                   // N fastest -> same-M co-resident
  const int tileM = xcd * 12 + (r >> 3);     // 0..95
  const int seg = tileM >> 5;                // 0..2
  gemm_core<1>(A, Bw + ((size_t)seg << 20), (void*)(Cb + ((size_t)seg << 23)),
               smem, tileM, tileM & 31, tileN);
}

// Output GEMM: f32 row-major C. grid (256,1,1), block 512, 48KB dyn LDS.
__global__ __launch_bounds__(512, 4) void gemm_out(
    const bf16_t* __restrict__ Ap, const bf16_t* __restrict__ Bp,
    float* __restrict__ Cp)
{
  extern __shared__ bf16_t smem[];
  const int xcd = blockIdx.x & 7;
  const int r   = blockIdx.x >> 3;           // 0..31
  const int tileN = r & 7;
  const int tileM = xcd * 4 + (r >> 3);      // 0..31
  gemm_core<0>(Ap, Bp, (void*)Cp, smem, tileM, tileM, tileN);
}

// ---------------------------------------------------------------------------
// Flash attention v4 (staged — R12 showed removing staging puts global-load
// latency on every MFMA's critical path: 114 µs, MfmaUtil 5%. Staged form
// keeps operands on the LDS fast path; 6 blocks/CU cross-hide the barriers).
// Q,K in [B,H,S,64]; V TRANSPOSED in [B,H,64,S]. Out [B,S,H*64] bf16.
// grid (H, S/64, B): XCD = h%8 -> per-XCD K/V set = 4MB = L2.
// ---------------------------------------------------------------------------
__global__ __launch_bounds__(256) void attn64(
    const bf16_t* __restrict__ Q,
    const bf16_t* __restrict__ Kv,
    const bf16_t* __restrict__ Vt,
    const int* __restrict__ valid_lens,
    bf16_t* __restrict__ O)
{
  const int h  = blockIdx.x;
  const int qt = blockIdx.y;
  const int b  = blockIdx.z;
  const int tid  = threadIdx.x;
  const int wave = tid >> 6;
  const int lane = tid & 63;
  const int quad = lane >> 4;
  const int l15  = lane & 15;

  const int L   = valid_lens[b];
  const int nkt = (L + 63) >> 6;

  const size_t base = ((size_t)(b * H_ + h)) * S_ * DH_;
  const bf16_t* Qp = Q  + base;
  const bf16_t* Kp = Kv + base;
  const bf16_t* Vp = Vt + base;     // [64][1024] per (b,h)

  __shared__ bf16_t KsA[64 * 32];   // K tile, d 0..31   [key][d]
  __shared__ bf16_t KsB[64 * 32];   // K tile, d 32..63
  __shared__ bf16_t VsA[64 * 32];   // V^T tile, keys 0..31  [d][key]
  __shared__ bf16_t VsB[64 * 32];   // V^T tile, keys 32..63
  __shared__ bf16_t Pb[4][16 * 72]; // per-wave P [q][key]
  bf16_t* const Pw = &Pb[wave][0];

  const int sr = tid >> 2;
  const int sj = (tid & 3) << 3;
  const int ldsOff = (wave * 64) * 8;      // wave-uniform LDS base offset

  const int qrow = qt * 64 + wave * 16 + l15;
  const bf16x8 qf0 = *(const bf16x8*)(Qp + (size_t)qrow * DH_ + quad * 8);
  const bf16x8 qf1 = *(const bf16x8*)(Qp + (size_t)qrow * DH_ + 32 + quad * 8);

  f32x4 o[4];
  float lsum[4];
#pragma unroll
  for (int r = 0; r < 4; ++r) {
    o[r] = (f32x4){0.f, 0.f, 0.f, 0.f};
    lsum[r] = 0.f;
  }

  for (int kt = 0; kt < nkt; ++kt) {
    const int k0 = kt * 64;

    __syncthreads();   // prior tile's LDS reads complete
    GLOAD_LDS16(Kp + (size_t)(k0 + sr) * DH_ + sj,      KsA + ldsOff);
    GLOAD_LDS16(Kp + (size_t)(k0 + sr) * DH_ + 32 + sj, KsB + ldsOff);
    GLOAD_LDS16(Vp + (size_t)sr * S_ + k0 + sj,         VsA + ldsOff);
    GLOAD_LDS16(Vp + (size_t)sr * S_ + k0 + 32 + sj,    VsB + ldsOff);
    __syncthreads();   // staging drained

    // ---- scores: S = Q K^T ----
    f32x4 sc[4];
#pragma unroll
    for (int n16 = 0; n16 < 4; ++n16) {
      const int row = (n16 * 16 + l15) * 32 + quad * 8;
      bf16x8 kf0 = *(const bf16x8*)(KsA + row);
      bf16x8 kf1 = *(const bf16x8*)(KsB + row);
      f32x4 s = (f32x4){0.f, 0.f, 0.f, 0.f};
      s = mfma_bf16(qf0, kf0, s);
      s = mfma_bf16(qf1, kf1, s);
      sc[n16] = s;
    }

    // ---- p = exp(s/8), mask tail tile ----
    if (k0 + 64 <= L) {
#pragma unroll
      for (int n16 = 0; n16 < 4; ++n16) {
#pragma unroll
        for (int r = 0; r < 4; ++r) {
          const float p = __expf(sc[n16][r] * 0.125f);
          lsum[r] += p;
          Pw[(quad * 4 + r) * 72 + n16 * 16 + l15] = (bf16_t)p;
        }
      }
    } else {
#pragma unroll
      for (int n16 = 0; n16 < 4; ++n16) {
        const bool valid = (k0 + n16 * 16 + l15) < L;
#pragma unroll
        for (int r = 0; r < 4; ++r) {
          const float p = valid ? __expf(sc[n16][r] * 0.125f) : 0.f;
          lsum[r] += p;
          Pw[(quad * 4 + r) * 72 + n16 * 16 + l15] = (bf16_t)p;
        }
      }
    }

    // ---- O += P @ V ----
    const bf16x8 pf0 = *(const bf16x8*)(Pw + l15 * 72 + quad * 8);
    const bf16x8 pf1 = *(const bf16x8*)(Pw + l15 * 72 + 32 + quad * 8);
#pragma unroll
    for (int dt = 0; dt < 4; ++dt) {
      const int row = (dt * 16 + l15) * 32 + quad * 8;
      bf16x8 vf0 = *(const bf16x8*)(VsA + row);
      bf16x8 vf1 = *(const bf16x8*)(VsB + row);
      o[dt] = mfma_bf16(pf0, vf0, o[dt]);
      o[dt] = mfma_bf16(pf1, vf1, o[dt]);
    }
  }

  // ---- row-sum reduce, normalize, write [B,S,H*64] ----
  float inv[4];
#pragma unroll
  for (int r = 0; r < 4; ++r) {
    float t = lsum[r];
    t += __shfl_xor(t, 1, 64);
    t += __shfl_xor(t, 2, 64);
    t += __shfl_xor(t, 4, 64);
    t += __shfl_xor(t, 8, 64);
    inv[r] = 1.f / t;
  }
  const int qout = qt * 64 + wave * 16 + quad * 4;
#pragma unroll
  for (int dt = 0; dt < 4; ++dt) {
#pragma unroll
    for (int r = 0; r < 4; ++r) {
      const float v = o[dt][r] * inv[r];
      O[((size_t)(b * S_ + qout + r)) * (H_ * DH_) + h * DH_ + dt * 16 + l15] = (bf16_t)v;
    }
  }
}

// ---------------------------------------------------------------------------
extern "C" void kernel_launch(void* const* d_in, const int* in_sizes, int n_in,
                              void* d_out, int out_size, void* d_ws, size_t ws_size,
                              hipStream_t stream) {
  const float* queries = (const float*)d_in[0];
  const float* keys    = (const float*)d_in[1];
  const float* values  = (const float*)d_in[2];
  const float* Wq      = (const float*)d_in[3];
  const float* Wk      = (const float*)d_in[4];
  const float* Wv      = (const float*)d_in[5];
  const float* Wo      = (const float*)d_in[6];
  const int* valid_lens = (const int*)d_in[7];
  float* out = (float*)d_out;

  bf16_t* ws = (bf16_t*)d_ws;
  const size_t MB = 1024 * 1024;     // elements (bf16)
  bf16_t* WqT = ws + 0 * MB;         // WqT,WkT,WvT contiguous (seg<<20)
  bf16_t* WkT = ws + 1 * MB;
  bf16_t* WvT = ws + 2 * MB;
  bf16_t* WoT = ws + 3 * MB;
  bf16_t* Qc  = ws + 4 * MB;         // Qc,Kc,Vc contiguous -> fused A 24576x1024
  bf16_t* Kc  = ws + 12 * MB;
  bf16_t* Vc  = ws + 20 * MB;
  bf16_t* Qb  = ws + 28 * MB;        // Qb,Kb,Vb contiguous (seg<<23)
  bf16_t* Kb  = ws + 36 * MB;
  bf16_t* Vb  = ws + 44 * MB;
  bf16_t* VbT = ws + 52 * MB;        // [B,H,64,S] transposed V
  bf16_t* Ab  = ws + 60 * MB;        // [B,S,1024] attn out  (total 136 MB)

  (void)hipFuncSetAttribute((const void*)gemm_proj,
                            hipFuncAttributeMaxDynamicSharedMemorySize, LDS_BYTES);
  (void)hipFuncSetAttribute((const void*)gemm_out,
                            hipFuncAttributeMaxDynamicSharedMemorySize, LDS_BYTES);

  transpose4<<<dim3(16, 16, 4), 256, 0, stream>>>(Wq, Wk, Wv, Wo, WqT, WkT, WvT, WoT);

  convert_qkv<<<dim3(4096, 3), 256, 0, stream>>>(queries, keys, values, Qc, Kc, Vc);

  gemm_proj<<<dim3(768, 1, 1), 512, LDS_BYTES, stream>>>(Qc, WqT, Qb);

  transposeV<<<dim3(16, 128), 256, 0, stream>>>(Vb, VbT);

  attn64<<<dim3(16, 16, 8), 256, 0, stream>>>(Qb, Kb, VbT, valid_lens, Ab);

  gemm_out<<<dim3(256, 1, 1), 512, LDS_BYTES, stream>>>(Ab, WoT, out);
}